// Round 1
// 1590.914 us; speedup vs baseline: 1.4034x; 1.4034x over previous
//
#include <hip/hip_runtime.h>
#include <stdint.h>

typedef unsigned int u32;
typedef unsigned short u16;

#define S_DIM 2048
#define D_DIM 64
#define BH    32
#define SLICE (S_DIM*D_DIM)      // 131072
#define NEL   (BH*SLICE)         // 4194304
#define CAPC  262144

// ---- workspace layout (bytes) ----
#define OFF_X1BF   0u            // 4M bf16 (ushort)        8 MB
#define OFF_X2BFT  8388608u      // 4M bf16, [bh][s][d]     8 MB
#define OFF_XM1T   16777216u     // [64][2048] f32          512 KB
#define OFF_XM2T   17301504u     // [64][2048] f32          512 KB
#define OFF_LR1    17825792u     // [2048][64] f32          512 KB
#define OFF_LR2T   18350080u     // [64][2048] f32          512 KB
#define OFF_G      18874368u     // 2 x 64x64 f32
#define OFF_P      18907136u     // 2 x 64x64 f32
#define OFF_HIST   18939904u     // 2 x 1024 u32
#define OFF_META   18948096u     // scalars
#define OFF_CAND   18948352u     // 2 x 262144 u32          2 MB
#define OFF_EIG    21045504u     // 2 x 10240 f64           160 KB
// total ~21.2 MB

#define M_BSEL  0
#define M_RBASE 2
#define M_CNT   4
#define M_MNEXT 6
#define M_T     8
#define M_SCALE 10

typedef short bf16x8 __attribute__((ext_vector_type(8)));
typedef float f32x4  __attribute__((ext_vector_type(4)));

__device__ __forceinline__ u16 f2bf(float f) {
  u32 u = __float_as_uint(f);
  u32 r = u + 0x7FFFu + ((u >> 16) & 1u);   // RNE, inputs finite
  return (u16)(r >> 16);
}

// ---------------- init: zero histograms / meta ----------------
__global__ void k_init(u32* hist, u32* meta) {
  int t = threadIdx.x;
  for (int i = t; i < 2048; i += 256) hist[i] = 0u;
  if (t < 16) meta[t] = (t == M_MNEXT || t == M_MNEXT+1) ? 0xFFFFFFFFu : 0u;
}

// -------- pass1 x1: mean (xm1T), bf16 convert, |x| histogram --------
__global__ void k_p1a(const float* __restrict__ x1, u16* __restrict__ x1bf,
                      float* __restrict__ xm1T, u32* __restrict__ hist) {
  __shared__ u32 lh[4][1024];
  int tid = threadIdx.x;
  for (int i = tid; i < 4096; i += 256) ((u32*)lh)[i] = 0u;
  __syncthreads();
  int e = blockIdx.x*256 + tid;            // 0..SLICE-1, j fast
  int j = e & 63, s = e >> 6;
  int rep = tid & 3;
  float sum = 0.f;
  for (int b = 0; b < BH; b++) {
    float v = x1[b*SLICE + e];
    sum += v;
    u32 bits = __float_as_uint(v) & 0x7FFFFFFFu;
    atomicAdd(&lh[rep][bits >> 21], 1u);
    x1bf[b*SLICE + e] = f2bf(v);
  }
  xm1T[j*S_DIM + s] = sum * (1.0f/32.0f);
  __syncthreads();
  for (int i = tid; i < 1024; i += 256) {
    u32 c = lh[0][i] + lh[1][i] + lh[2][i] + lh[3][i];
    if (c) atomicAdd(&hist[i], c);
  }
}

// -------- pass1 x2: mean (xm2T) + histogram --------
__global__ void k_p1b(const float* __restrict__ x2, float* __restrict__ xm2T,
                      u32* __restrict__ hist) {
  __shared__ u32 lh[4][1024];
  int tid = threadIdx.x;
  for (int i = tid; i < 4096; i += 256) ((u32*)lh)[i] = 0u;
  __syncthreads();
  int e = blockIdx.x*256 + tid;            // slice layout [64][2048], s fast
  int rep = tid & 3;
  float sum = 0.f;
  for (int b = 0; b < BH; b++) {
    float v = x2[b*SLICE + e];
    sum += v;
    u32 bits = __float_as_uint(v) & 0x7FFFFFFFu;
    atomicAdd(&lh[rep][bits >> 21], 1u);
  }
  xm2T[e] = sum * (1.0f/32.0f);
  __syncthreads();
  for (int i = tid; i < 1024; i += 256) {
    u32 c = lh[0][i] + lh[1][i] + lh[2][i] + lh[3][i];
    if (c) atomicAdd(&hist[i], c);
  }
}

// -------- transpose x2 -> bf16 [bh][n=s][k=d] for MFMA B-frags --------
__global__ void k_tr(const float* __restrict__ x2, u16* __restrict__ x2bfT) {
  __shared__ float tile[64][65];
  int bh = blockIdx.x >> 5, st = blockIdx.x & 31;
  int s0 = st * 64;
  int tid = threadIdx.x;
  const float* src = x2 + bh*SLICE;
  for (int r = 0; r < 16; r++) {
    int idx = r*256 + tid;
    int d = idx >> 6, s = idx & 63;        // s fast: coalesced read
    tile[d][s] = src[d*S_DIM + s0 + s];
  }
  __syncthreads();
  u16* dst = x2bfT + bh*SLICE;
  for (int r = 0; r < 16; r++) {
    int idx = r*256 + tid;
    int d = idx & 63, s = idx >> 6;        // d fast: coalesced write
    dst[(s0+s)*64 + d] = f2bf(tile[d][s]);
  }
}

// -------- select coarse bin containing rank k --------
__global__ void k_select1(const u32* __restrict__ hist, u32* __restrict__ meta) {
  int t = blockIdx.x, tid = threadIdx.x;
  __shared__ u32 lh[1024];
  __shared__ u32 ps[256];
  const u32* h = hist + t*1024;
  for (int i = tid; i < 1024; i += 256) lh[i] = h[i];
  __syncthreads();
  u32 s = 0;
  for (int u = 0; u < 4; u++) s += lh[tid*4+u];
  ps[tid] = s;
  __syncthreads();
  if (tid == 0) {
    double hq = (1.0 - 0.01) * (double)(NEL - 1);
    u32 k = (u32)hq;
    u32 cum = 0; int blk = 0;
    while (cum + ps[blk] <= k) { cum += ps[blk]; blk++; }
    int bin = blk*4;
    while (cum + lh[bin] <= k) { cum += lh[bin]; bin++; }
    meta[M_BSEL + t]  = (u32)bin;
    meta[M_RBASE + t] = cum;
  }
}

// -------- collect candidates in selected bin + min of higher bins --------
// Block-aggregated: LDS staging + ONE global atomicAdd per block (was: one
// contended global atomicAdd per matching element -> 741 us of RMW serialization).
__global__ void k_collect(const float* __restrict__ x1, const float* __restrict__ x2,
                          u32* __restrict__ meta, u32* __restrict__ cand) {
  __shared__ u32 sbuf[2048];               // worst case: every element matches
  __shared__ u32 red[256];
  __shared__ u32 scount, sbase;
  int tid = threadIdx.x;
  int base = blockIdx.x * 2048;            // 4096 blocks over 2*NEL
  int tensor = (base >= NEL) ? 1 : 0;
  const float* src = tensor ? x2 : x1;
  int off = tensor ? base - NEL : base;
  u32 bsel = meta[M_BSEL + tensor];
  if (tid == 0) scount = 0u;
  __syncthreads();
  u32 localmin = 0xFFFFFFFFu;
  for (int r = 0; r < 8; r++) {
    u32 bits = __float_as_uint(src[off + r*256 + tid]) & 0x7FFFFFFFu;
    u32 top = bits >> 21;
    if (top == bsel) { u32 p = atomicAdd(&scount, 1u); sbuf[p] = bits; }
    else if (top > bsel) localmin = min(localmin, bits);
  }
  red[tid] = localmin;
  __syncthreads();                          // scount final + red populated
  for (int w = 128; w > 0; w >>= 1) { if (tid < w) red[tid] = min(red[tid], red[tid+w]); __syncthreads(); }
  if (tid == 0) {
    if (red[0] != 0xFFFFFFFFu) atomicMin(&meta[M_MNEXT + tensor], red[0]);
    sbase = atomicAdd(&meta[M_CNT + tensor], scount);   // one RMW per block
  }
  __syncthreads();
  u32 cnt = scount, b0 = sbase;
  u32* cd = cand + tensor*CAPC;
  for (u32 i = tid; i < cnt; i += 256) {
    u32 p = b0 + i;
    if (p < CAPC) cd[p] = sbuf[i];
  }
}

// -------- exact order statistics a[k], a[k+1] -> threshold t --------
__global__ void k_fsel(const u32* __restrict__ cand_all, u32* __restrict__ meta) {
  int t = blockIdx.x, tid = threadIdx.x;
  const u32* cd = cand_all + t*CAPC;
  u32 total = meta[M_CNT + t];
  u32 n = total < CAPC ? total : CAPC;
  u32 rbase = meta[M_RBASE + t];
  double hq = (1.0 - 0.01) * (double)(NEL - 1);
  u32 k = (u32)hq;
  double frac = hq - (double)k;
  u32 r = k - rbase;
  __shared__ u32 h2[2048];
  __shared__ u32 ps[256];
  __shared__ u32 sbin[2], sbase[2], sres;
  for (int i = tid; i < 2048; i += 256) h2[i] = 0u;
  __syncthreads();
  for (u32 i = tid; i < n; i += 256) atomicAdd(&h2[(cd[i] >> 10) & 0x7FFu], 1u);
  __syncthreads();
  u32 psum = 0;
  for (int u = 0; u < 8; u++) psum += h2[tid*8+u];
  ps[tid] = psum;
  __syncthreads();
  if (tid == 0) {
    for (int q = 0; q < 2; q++) {
      u32 rank = r + q;
      if (rank >= total) { sbin[q] = 0xFFFFFFFFu; sbase[q] = 0; continue; }
      u32 cum = 0; int blk = 0;
      while (cum + ps[blk] <= rank) { cum += ps[blk]; blk++; }
      int bin = blk*8;
      while (cum + h2[bin] <= rank) { cum += h2[bin]; bin++; }
      sbin[q] = (u32)bin; sbase[q] = cum;
    }
  }
  __syncthreads();
  u32 vals[2];
  u32 bsel = meta[M_BSEL + t];
  for (int q = 0; q < 2; q++) {
    u32 bq = sbin[q];                       // uniform
    if (bq != 0xFFFFFFFFu) {
      __syncthreads();
      for (int i = tid; i < 1024; i += 256) h2[i] = 0u;
      __syncthreads();
      for (u32 i = tid; i < n; i += 256) {
        u32 c = cd[i];
        if (((c >> 10) & 0x7FFu) == bq) atomicAdd(&h2[c & 0x3FFu], 1u);
      }
      __syncthreads();
      if (tid == 0) {
        u32 rank = r + q - sbase[q];
        u32 cum = 0; int b3 = 0;
        while (cum + h2[b3] <= rank) { cum += h2[b3]; b3++; }
        sres = (bsel << 21) | (bq << 10) | (u32)b3;
      }
      __syncthreads();
      vals[q] = sres;
    } else {
      vals[q] = meta[M_MNEXT + t];
    }
  }
  if (tid == 0) {
    double a0 = (double)__uint_as_float(vals[0]);
    double a1 = (double)__uint_as_float(vals[1]);
    meta[M_T + t] = __float_as_uint((float)(a0 + frac*(a1 - a0)));
  }
}

// -------- Gram G = xm^T xm (both tensors; xmT is [64][2048]) --------
__global__ void k_gram(const float* __restrict__ xm1T, const float* __restrict__ xm2T,
                       float* __restrict__ G) {
  int t = blockIdx.x >> 6, i = blockIdx.x & 63, tid = threadIdx.x;
  const float* xm = t ? xm2T : xm1T;
  float acc[64];
  #pragma unroll
  for (int j = 0; j < 64; j++) acc[j] = 0.f;
  for (int c = 0; c < 8; c++) {
    int s = c*256 + tid;
    float vi = xm[i*S_DIM + s];
    #pragma unroll
    for (int j = 0; j < 64; j++) acc[j] += xm[j*S_DIM + s] * vi;
  }
  __shared__ float red[256*65];
  for (int j = 0; j < 64; j++) red[tid*65 + j] = acc[j];
  __syncthreads();
  if (tid < 64) {
    float ssum = 0.f;
    for (int c = 0; c < 256; c++) ssum += red[c*65 + tid];
    G[t*4096 + i*64 + tid] = ssum;
  }
}

// -------- eigen path: top-16 projector P of G via orthogonal iteration --------
__device__ void eigen_path(int t, const float* __restrict__ G, float* __restrict__ P,
                           double* __restrict__ eig) {
  int tid = threadIdx.x;
  double* EA = eig + t*10240;
  double* EB = EA + 4096;
  double* EZ = EA + 8192;
  double* EQ = EA + 8192 + 1024;
  for (int i = tid; i < 4096; i += 256) EA[i] = (double)G[t*4096 + i] * (1.0/64.0);
  __syncthreads();
  // 5 squarings -> B32 = (G/64)^32  (fp64, via global+L1; no big LDS)
  double* src = EA; double* dst = EB;
  for (int sq = 0; sq < 5; sq++) {
    int i = tid >> 2, j0 = (tid & 3) * 16;
    double o[16];
    #pragma unroll
    for (int u = 0; u < 16; u++) o[u] = 0.0;
    for (int kk = 0; kk < 64; kk++) {
      double a = src[i*64 + kk];
      #pragma unroll
      for (int u = 0; u < 16; u++) o[u] += a * src[kk*64 + j0 + u];
    }
    #pragma unroll
    for (int u = 0; u < 16; u++) dst[i*64 + j0 + u] = o[u];
    __syncthreads();
    double* tmp = src; src = dst; dst = tmp;
  }
  double* B32 = src;
  // Q0: deterministic pseudo-random
  for (int idx = tid; idx < 1024; idx += 256) {
    int i = idx >> 4, j = idx & 15;
    u32 h = ((u32)i * 73856093u) ^ ((u32)j * 19349663u) ^ 0x9E3779B9u;
    h ^= h >> 13; h *= 0x85EBCA6Bu; h ^= h >> 16;
    EQ[idx] = ((double)(h & 0xFFFFu) - 32768.0) / 32768.0;
  }
  __syncthreads();
  __shared__ double Ssh[16][17];
  __shared__ double Lsh[16][17];
  for (int stage = 0; stage < 20; stage++) {
    { // Z = B32 * Q
      int i = tid >> 2, j0 = (tid & 3) * 4;
      double o[4] = {0.0, 0.0, 0.0, 0.0};
      for (int kk = 0; kk < 64; kk++) {
        double b = B32[i*64 + kk];
        #pragma unroll
        for (int u = 0; u < 4; u++) o[u] += b * EQ[kk*16 + j0 + u];
      }
      __syncthreads();   // all EQ reads done before trsm rewrites later; also orders below
      #pragma unroll
      for (int u = 0; u < 4; u++) EZ[i*16 + j0 + u] = o[u];
      __syncthreads();
    }
    { // S = Z^T Z
      int a = tid >> 4, b = tid & 15;
      double acc = 0.0;
      for (int kk = 0; kk < 64; kk++) acc += EZ[kk*16 + a] * EZ[kk*16 + b];
      Ssh[a][b] = acc;
      __syncthreads();
    }
    // Cholesky (lower), clamped
    for (int j = 0; j < 16; j++) {
      if (tid < 16 && tid >= j) {
        double piv = Ssh[j][j];
        piv = piv > 1e-280 ? piv : 1e-280;
        double d = sqrt(piv);
        Lsh[tid][j] = (tid == j) ? d : Ssh[tid][j] / d;
      }
      __syncthreads();
      int a = tid >> 4, b = tid & 15;
      if (a > j && b > j && b <= a) Ssh[a][b] -= Lsh[a][j] * Lsh[b][j];
      __syncthreads();
    }
    // Qnew = Z * L^-T  (row-local, barrier-free)
    if (tid < 64) {
      double q[16];
      #pragma unroll
      for (int j = 0; j < 16; j++) {
        double v = EZ[tid*16 + j];
        #pragma unroll
        for (int m = 0; m < 16; m++) if (m < j) v -= q[m] * Lsh[j][m];
        q[j] = v / Lsh[j][j];
      }
      #pragma unroll
      for (int j = 0; j < 16; j++) EQ[tid*16 + j] = q[j];
    }
    __syncthreads();
  }
  { // P = Q Q^T (f32)
    int i = tid >> 2, j0 = (tid & 3) * 16;
    for (int u = 0; u < 16; u++) {
      double acc = 0.0;
      #pragma unroll
      for (int m = 0; m < 16; m++) acc += EQ[i*16 + m] * EQ[(j0+u)*16 + m];
      P[t*4096 + i*64 + j0 + u] = (float)acc;
    }
  }
}

// -------- fused: bf16 MFMA GEMM (blocks 2..) + eigen (blocks 0,1) --------
__global__ void __launch_bounds__(256) k_fused(const u16* __restrict__ x1bf,
                                               const u16* __restrict__ x2bfT,
                                               const float* __restrict__ G,
                                               float* __restrict__ P,
                                               double* __restrict__ eig,
                                               float* __restrict__ out) {
  if (blockIdx.x < 2) { eigen_path(blockIdx.x, G, P, eig); return; }
  int bid = blockIdx.x - 2;
  int batch = bid >> 8;
  int tile = bid & 255;
  int ti = tile >> 4, tj = tile & 15;
  int tid = threadIdx.x, lane = tid & 63, wave = tid >> 6;
  int wr = wave >> 1, wc = wave & 1;
  int m16 = lane & 15, quad = lane >> 4;
  const u16* A  = x1bf  + batch*SLICE;
  const u16* Bm = x2bfT + batch*SLICE;
  int row0 = ti*128 + wr*64;
  int col0 = tj*128 + wc*64;
  f32x4 acc[4][4];
  #pragma unroll
  for (int si = 0; si < 4; si++)
    #pragma unroll
    for (int sj = 0; sj < 4; sj++) acc[si][sj] = (f32x4){0.f, 0.f, 0.f, 0.f};
  #pragma unroll
  for (int kh = 0; kh < 2; kh++) {
    int k0 = kh*32 + quad*8;
    bf16x8 af[4], bfr[4];
    #pragma unroll
    for (int si = 0; si < 4; si++)
      af[si] = *reinterpret_cast<const bf16x8*>(A + (row0 + si*16 + m16)*64 + k0);
    #pragma unroll
    for (int sj = 0; sj < 4; sj++)
      bfr[sj] = *reinterpret_cast<const bf16x8*>(Bm + (col0 + sj*16 + m16)*64 + k0);
    #pragma unroll
    for (int si = 0; si < 4; si++)
      #pragma unroll
      for (int sj = 0; sj < 4; sj++)
        acc[si][sj] = __builtin_amdgcn_mfma_f32_16x16x32_bf16(af[si], bfr[sj], acc[si][sj], 0, 0, 0);
  }
  float* C = out + (size_t)batch * S_DIM * S_DIM;
  #pragma unroll
  for (int si = 0; si < 4; si++)
    #pragma unroll
    for (int sj = 0; sj < 4; sj++) {
      int col = col0 + sj*16 + m16;
      #pragma unroll
      for (int r = 0; r < 4; r++) {
        int row = row0 + si*16 + quad*4 + r;
        C[(size_t)row * S_DIM + col] = acc[si][sj][r];
      }
    }
}

// -------- LR = xm * P (both layouts) --------
__global__ void k_lr(const float* __restrict__ xm1T, const float* __restrict__ xm2T,
                     const float* __restrict__ P, float* __restrict__ LR1,
                     float* __restrict__ LR2T) {
  int gid = blockIdx.x*256 + threadIdx.x;   // 0..2*SLICE-1
  if (gid < SLICE) {
    int s = gid >> 6, d = gid & 63;
    float acc = 0.f;
    for (int k = 0; k < 64; k++) acc += xm1T[k*S_DIM + s] * P[k*64 + d];
    LR1[gid] = acc;
  } else {
    int g2 = gid - SLICE;
    int d = g2 >> 11, s = g2 & 2047;
    const float* Pp = P + 4096;
    float acc = 0.f;
    for (int k = 0; k < 64; k++) acc += xm2T[k*S_DIM + s] * Pp[k*64 + d];
    LR2T[g2] = acc;
  }
}

// -------- scale = max|masked - LR| --------
__global__ void k_p3(const float* __restrict__ x1, const float* __restrict__ x2,
                     const float* __restrict__ LR1, const float* __restrict__ LR2T,
                     u32* __restrict__ meta) {
  int tid = threadIdx.x;
  int base = blockIdx.x * 2048;
  int tensor = (base >= NEL) ? 1 : 0;
  const float* src = tensor ? x2 : x1;
  const float* lr  = tensor ? LR2T : LR1;
  int off = tensor ? base - NEL : base;
  float tq = __uint_as_float(meta[M_T + tensor]);
  float mx = 0.f;
  for (int r = 0; r < 8; r++) {
    int e = off + r*256 + tid;
    float v = src[e];
    float l = lr[e & (SLICE-1)];
    float masked = (fabsf(v) > tq) ? 0.f : v;
    mx = fmaxf(mx, fabsf(masked - l));
  }
  __shared__ float red[256];
  red[tid] = mx;
  __syncthreads();
  for (int w = 128; w > 0; w >>= 1) { if (tid < w) red[tid] = fmaxf(red[tid], red[tid+w]); __syncthreads(); }
  if (tid == 0) atomicMax(&meta[M_SCALE + tensor], __float_as_uint(red[0]));
}

// -------- compress + decompress -> x1_hat, x2_hat --------
__global__ void k_p4(const float* __restrict__ x1, const float* __restrict__ x2,
                     const float* __restrict__ LR1, const float* __restrict__ LR2T,
                     const u32* __restrict__ meta, float* __restrict__ out) {
  int tid = threadIdx.x;
  int base = blockIdx.x * 2048;
  int tensor = (base >= NEL) ? 1 : 0;
  const float* src = tensor ? x2 : x1;
  const float* lr  = tensor ? LR2T : LR1;
  int off = tensor ? base - NEL : base;
  float tq = __uint_as_float(meta[M_T + tensor]);
  float sc = __uint_as_float(meta[M_SCALE + tensor]) / 127.0f;
  float* dst = out + 134217728u + (size_t)tensor * NEL;
  for (int r = 0; r < 8; r++) {
    int e = off + r*256 + tid;
    float v = src[e];
    float l = lr[e & (SLICE-1)];
    float o = (fabsf(v) > tq) ? v : 0.f;
    float sub = v - o - l;
    float q = rintf(sub / sc);
    q = fminf(127.f, fmaxf(-127.f, q));
    dst[e] = o + q*sc + l;
  }
}

extern "C" void kernel_launch(void* const* d_in, const int* in_sizes, int n_in,
                              void* d_out, int out_size, void* d_ws, size_t ws_size,
                              hipStream_t stream) {
  const float* x1 = (const float*)d_in[0];
  const float* x2 = (const float*)d_in[1];
  float* out = (float*)d_out;
  char* ws = (char*)d_ws;
  u16*   x1bf  = (u16*)  (ws + OFF_X1BF);
  u16*   x2bfT = (u16*)  (ws + OFF_X2BFT);
  float* xm1T  = (float*)(ws + OFF_XM1T);
  float* xm2T  = (float*)(ws + OFF_XM2T);
  float* LR1   = (float*)(ws + OFF_LR1);
  float* LR2T  = (float*)(ws + OFF_LR2T);
  float* G     = (float*)(ws + OFF_G);
  float* P     = (float*)(ws + OFF_P);
  u32*   hist  = (u32*)  (ws + OFF_HIST);
  u32*   meta  = (u32*)  (ws + OFF_META);
  u32*   cand  = (u32*)  (ws + OFF_CAND);
  double* eig  = (double*)(ws + OFF_EIG);

  k_init    <<<1,    256, 0, stream>>>(hist, meta);
  k_p1a     <<<512,  256, 0, stream>>>(x1, x1bf, xm1T, hist);
  k_p1b     <<<512,  256, 0, stream>>>(x2, xm2T, hist + 1024);
  k_tr      <<<1024, 256, 0, stream>>>(x2, x2bfT);
  k_select1 <<<2,    256, 0, stream>>>(hist, meta);
  k_collect <<<4096, 256, 0, stream>>>(x1, x2, meta, cand);
  k_fsel    <<<2,    256, 0, stream>>>(cand, meta);
  k_gram    <<<128,  256, 0, stream>>>(xm1T, xm2T, G);
  k_fused   <<<8194, 256, 0, stream>>>(x1bf, x2bfT, G, P, eig, out);
  k_lr      <<<1024, 256, 0, stream>>>(xm1T, xm2T, P, LR1, LR2T);
  k_p3      <<<4096, 256, 0, stream>>>(x1, x2, LR1, LR2T, meta);
  k_p4      <<<4096, 256, 0, stream>>>(x1, x2, LR1, LR2T, meta, out);
}